// Round 9
// baseline (181.340 us; speedup 1.0000x reference)
//
#include <hip/hip_runtime.h>

// Problem constants (RefinementLayer1): B=2, L=192, D=768, NC=4, H=256
#define LSEQ 192
#define DIM  768
#define NCASE 4
#define HID  256
#define BATCH 2

typedef float  floatx4 __attribute__((ext_vector_type(4)));
typedef __bf16 bf16x8  __attribute__((ext_vector_type(8)));

// Pade [5/4] tanh + clamp: 1 trans (rcp) + ~8 full-rate VALU, vs 2 trans for
// the exp2 form. Max err ~1.1e-3 near |x|~3.7 (below bf16 rounding noise);
// exact saturation via clamp. R7 counters showed VALU time == tanh trans
// issue time (36 us), so halving trans halves the VALU floor.
__device__ __forceinline__ float tanh_pade(float x) {
    float x2 = x * x;
    float num = x * (945.0f + x2 * (105.0f + x2));
    float den = 945.0f + x2 * (420.0f + x2 * 15.0f);
    float r = num * __builtin_amdgcn_rcpf(den);
    return __builtin_fminf(1.0f, __builtin_fmaxf(-1.0f, r));   // v_med3
}

// Workgroup barrier draining ONLY lgkmcnt (LDS); global prefetches stay in
// flight. 0xC07F = vmcnt(63) expcnt(7) lgkmcnt(0).
__device__ __forceinline__ void barrier_lds_only() {
    __builtin_amdgcn_sched_barrier(0);
    __builtin_amdgcn_s_waitcnt(0xC07F);
    __builtin_amdgcn_s_barrier();
    __builtin_amdgcn_sched_barrier(0);
}

template <int CTRL>
__device__ __forceinline__ float dpp_add(float v) {
    int x = __builtin_amdgcn_update_dpp(0, __builtin_bit_cast(int, v),
                                        CTRL, 0xF, 0xF, true);
    return v + __builtin_bit_cast(float, x);
}
__device__ __forceinline__ float row16_reduce(float v) {
    v = dpp_add<0xB1>(v);    // quad_perm xor1
    v = dpp_add<0x4E>(v);    // quad_perm xor2
    v = dpp_add<0x141>(v);   // row_half_mirror
    v = dpp_add<0x140>(v);   // row_mirror
    return v;
}

// ---------------------------------------------------------------------------
// MFMA fragment layouts (m89/m91-verified, 16x16x32 bf16):
//   A: lane holds A[m = lane&15][k = (lane>>4)*8 + j]   (bf16x8)
//   B: lane holds B[k = (lane>>4)*8 + j][h = lane&15]   (bf16x8)
//   C/D: lane reg holds D[row = (lane>>4)*4 + reg][col = lane&15]
// ---------------------------------------------------------------------------

// ---------------------------------------------------------------------------
// Kernel 1 "prep": two jobs by blockIdx:
//  blocks [0,480):  lin GEMM, 4 independent waves/block; wave = one (rt,cg)
//    unit: 16 rows x 16 cols of lin = seq @ [Wp|Wa] + bias (UNscaled now).
//    seq/W converted to bf16 hi/lo in-register, MFMA hh+lh+hl. Barrier-free.
//  blocks [480,624): pack Wmid/bmid -> Bpack bf16 B-frags (unscaled).
// ---------------------------------------------------------------------------
__global__ __launch_bounds__(256) void prep(
    const float* __restrict__ seq, const float* __restrict__ Wp,
    const float* __restrict__ Wa,  const float* __restrict__ bp,
    const float* __restrict__ ba,  const float* __restrict__ Wmid,
    const float* __restrict__ bmid,
    float* __restrict__ lin, bf16x8* __restrict__ Bpack)
{
    const int blk = blockIdx.x;
    const int tid = threadIdx.x;

    if (blk >= 480) {                      // ---- pack job
        int u = (blk - 480) * 256 + tid;   // 0..36863 (one bf16x8 each)
        int lane = u & 63, f = u >> 6;
        int ct = f & 15, nk = f >> 4;      // nk = n*9 + kc
        int kc = nk % 9, n = nk / 9;
        int h = ct * 16 + (lane & 15);
        int kbase = kc * 32 + ((lane >> 4) & 3) * 8;
        bf16x8 v;
        #pragma unroll
        for (int j = 0; j < 8; j++) {
            int k = kbase + j;
            float x;
            if (k < 260)       x = Wmid[(size_t)(n * 260 + k) * 256 + h];
            else if (k == 260) x = bmid[n * 256 + h];
            else               x = 0.0f;
            v[j] = (__bf16)x;
        }
        Bpack[u] = v;
        return;
    }

    // ---- lin GEMM job: unit u = blk*4 + wave, rt = u/80, cg = u%80
    const int w = tid >> 6, lane = tid & 63;
    const int u = blk * 4 + w;
    const int rt = u / 80, cg = u % 80;
    const int quad  = lane >> 4;
    const int col16 = lane & 15;

    const int arow = rt * 16 + col16;          // A: m = lane&15
    const int col  = cg * 16 + col16;          // output col 0..1279
    const float* aptr = seq + (size_t)arow * DIM + quad * 8;
    const float* wbase = (cg < 16) ? (Wp + col) : (Wa + (col - 256));
    const int    wstr  = (cg < 16) ? HID : (NCASE * HID);

    floatx4 acc = {};
    floatx4 a0 = *(const floatx4*)(aptr);
    floatx4 a1 = *(const floatx4*)(aptr + 4);
    float bv[8];
    #pragma unroll
    for (int j = 0; j < 8; j++) bv[j] = wbase[(size_t)(quad * 8 + j) * wstr];

    #pragma unroll
    for (int kc = 0; kc < 24; kc++) {
        bf16x8 ah, al, bh, bl;
        #pragma unroll
        for (int j = 0; j < 4; j++) {
            __bf16 h0 = (__bf16)a0[j];
            ah[j] = h0; al[j] = (__bf16)(a0[j] - (float)h0);
            __bf16 h1 = (__bf16)a1[j];
            ah[4 + j] = h1; al[4 + j] = (__bf16)(a1[j] - (float)h1);
        }
        #pragma unroll
        for (int j = 0; j < 8; j++) {
            __bf16 h = (__bf16)bv[j];
            bh[j] = h; bl[j] = (__bf16)(bv[j] - (float)h);
        }
        if (kc < 23) {
            a0 = *(const floatx4*)(aptr + (kc + 1) * 32);
            a1 = *(const floatx4*)(aptr + (kc + 1) * 32 + 4);
            #pragma unroll
            for (int j = 0; j < 8; j++)
                bv[j] = wbase[(size_t)((kc + 1) * 32 + quad * 8 + j) * wstr];
        }
        acc = __builtin_amdgcn_mfma_f32_16x16x32_bf16(ah, bh, acc, 0, 0, 0);
        acc = __builtin_amdgcn_mfma_f32_16x16x32_bf16(al, bh, acc, 0, 0, 0);
        acc = __builtin_amdgcn_mfma_f32_16x16x32_bf16(ah, bl, acc, 0, 0, 0);
    }
    const float bias = (cg < 16) ? bp[col] : ba[col - 256];
    #pragma unroll
    for (int reg = 0; reg < 4; reg++)
        lin[(size_t)(rt * 16 + quad * 4 + reg) * 1280 + col] = acc[reg] + bias;
}

// ---------------------------------------------------------------------------
// Kernel 2: fused main. Block = 4 waves, 64 rows (8p x 8a) x 256 cols, fixed
// (b,n). A SHARED via LDS; cols SPLIT across waves (wave w owns ct
// w*4..w*4+3; B global->regs per phase, non-redundant, L2-hot). TWO-CHUNK
// phases: gen av(next 2 chunks) -> 32 MFMA -> ONE lgkm-only barrier. 4 tanh
// phases + folded bs/bmid chunk (Afold, written in phase 3). Epilogue:
// tanh_pade(acc).Wout, DPP reduce, cross-wave LDS combine, store.
// ---------------------------------------------------------------------------
__global__ __launch_bounds__(256, 2) void refine_main(
    const float* __restrict__ lin,        // [384][1280]
    const float* __restrict__ base_score, // [B][L][NC][L]
    const float* __restrict__ Wout,       // [NC][256]
    const bf16x8* __restrict__ Bpack,     // packed Wmid frags
    float* __restrict__ out)              // [B][L][NC][L]
{
    const int bx = blockIdx.x;            // 576 = 24*24
    const int n  = blockIdx.y;
    const int b  = blockIdx.z;
    const int ptile = bx / 24, atile = bx % 24;
    const int p0 = ptile * 8, a0r = atile * 8;

    const int tid   = threadIdx.x;
    const int w     = tid >> 6;
    const int lane  = tid & 63;
    const int quad  = lane >> 4;
    const int col16 = lane & 15;

    __shared__ __align__(16) __bf16 Abuf[2][2 * 2048];  // 2 bufs x 2 chunks, 16 KB
    __shared__ __align__(16) __bf16 Afold[2048];        // folded chunk, 4 KB
    __shared__ float red[4][64];

    // A-gen slot: row = w*16 + col16, k-slice quad*8..+7 per chunk
    const int row_gen = w * 16 + col16;
    const int pg = p0 + (row_gen >> 3), ag = a0r + (row_gen & 7);
    const float* hp_ptr = lin + (size_t)(b * LSEQ + pg) * 1280 + quad * 8;
    const float* ha_ptr = lin + (size_t)(b * LSEQ + ag) * 1280 + 256 + n * 256 + quad * 8;

    // B frags for wave w: bbase[(kc*16 + ct)*64], ct in [0,4)
    const bf16x8* bbase = Bpack + ((size_t)(n * 9) * 16 + w * 4) * 64 + lane;

    float bs4[4], wo[4];
    #pragma unroll
    for (int j = 0; j < 4; j++)
        bs4[j] = base_score[((size_t)(b * LSEQ + pg) * NCASE + j) * LSEQ + ag];
    #pragma unroll
    for (int ct = 0; ct < 4; ct++)
        wo[ct] = Wout[n * 256 + w * 64 + ct * 16 + col16];

    // ---- prologue: gen chunks 0,1 into Abuf[0]; preload chunk 2,3 inputs
    floatx4 hpA0, hpA1, haA0, haA1, hpB0, hpB1, haB0, haB1;
    hpA0 = *(const floatx4*)(hp_ptr);       hpA1 = *(const floatx4*)(hp_ptr + 4);
    haA0 = *(const floatx4*)(ha_ptr);       haA1 = *(const floatx4*)(ha_ptr + 4);
    hpB0 = *(const floatx4*)(hp_ptr + 32);  hpB1 = *(const floatx4*)(hp_ptr + 36);
    haB0 = *(const floatx4*)(ha_ptr + 32);  haB1 = *(const floatx4*)(ha_ptr + 36);
    {
        floatx4 s0 = hpA0 + haA0, s1 = hpA1 + haA1;
        floatx4 t0 = hpB0 + haB0, t1 = hpB1 + haB1;
        bf16x8 av, bv2;
        #pragma unroll
        for (int j = 0; j < 4; j++) {
            av[j]      = (__bf16)tanh_pade(s0[j]);
            av[4 + j]  = (__bf16)tanh_pade(s1[j]);
            bv2[j]     = (__bf16)tanh_pade(t0[j]);
            bv2[4 + j] = (__bf16)tanh_pade(t1[j]);
        }
        *(bf16x8*)&Abuf[0][tid * 8] = av;
        *(bf16x8*)&Abuf[0][2048 + tid * 8] = bv2;
    }
    // inputs for chunks 2,3 (genned during phase 0)
    hpA0 = *(const floatx4*)(hp_ptr + 64);  hpA1 = *(const floatx4*)(hp_ptr + 68);
    haA0 = *(const floatx4*)(ha_ptr + 64);  haA1 = *(const floatx4*)(ha_ptr + 68);
    hpB0 = *(const floatx4*)(hp_ptr + 96);  hpB1 = *(const floatx4*)(hp_ptr + 100);
    haB0 = *(const floatx4*)(ha_ptr + 96);  haB1 = *(const floatx4*)(ha_ptr + 100);
    barrier_lds_only();

    floatx4 acc[4][4] = {};   // [rt][ct]

    #pragma unroll
    for (int ph = 0; ph < 4; ph++) {
        // B frags for this phase's two chunks (L2-hot; consumed after gen)
        bf16x8 b0[4], b1[4];
        #pragma unroll
        for (int ct = 0; ct < 4; ct++) {
            b0[ct] = bbase[((2 * ph) * 16 + ct) * 64];
            b1[ct] = bbase[((2 * ph + 1) * 16 + ct) * 64];
        }

        // generate next phase's A (chunks 2ph+2, 2ph+3) or the folded chunk
        if (ph < 3) {
            floatx4 s0 = hpA0 + haA0, s1 = hpA1 + haA1;
            floatx4 t0 = hpB0 + haB0, t1 = hpB1 + haB1;
            if (ph < 2) {   // preload inputs for chunks 2ph+4, 2ph+5
                hpA0 = *(const floatx4*)(hp_ptr + (2 * ph + 4) * 32);
                hpA1 = *(const floatx4*)(hp_ptr + (2 * ph + 4) * 32 + 4);
                haA0 = *(const floatx4*)(ha_ptr + (2 * ph + 4) * 32);
                haA1 = *(const floatx4*)(ha_ptr + (2 * ph + 4) * 32 + 4);
                hpB0 = *(const floatx4*)(hp_ptr + (2 * ph + 5) * 32);
                hpB1 = *(const floatx4*)(hp_ptr + (2 * ph + 5) * 32 + 4);
                haB0 = *(const floatx4*)(ha_ptr + (2 * ph + 5) * 32);
                haB1 = *(const floatx4*)(ha_ptr + (2 * ph + 5) * 32 + 4);
            }
            bf16x8 av, bv2;
            #pragma unroll
            for (int j = 0; j < 4; j++) {
                av[j]      = (__bf16)tanh_pade(s0[j]);
                av[4 + j]  = (__bf16)tanh_pade(s1[j]);
                bv2[j]     = (__bf16)tanh_pade(t0[j]);
                bv2[4 + j] = (__bf16)tanh_pade(t1[j]);
            }
            __bf16* buf = Abuf[(ph + 1) & 1];
            *(bf16x8*)&buf[tid * 8] = av;
            *(bf16x8*)&buf[2048 + tid * 8] = bv2;
        } else {            // folded chunk: A = [bs(4), 1, 0...]
            bf16x8 av = {};
            if (quad == 0) {
                #pragma unroll
                for (int j = 0; j < 4; j++) av[j] = (__bf16)bs4[j];
                av[4] = (__bf16)1.0f;
            }
            *(bf16x8*)&Afold[tid * 8] = av;
        }

        // MFMA this phase from Abuf[ph&1] (visible via previous barrier)
        const __bf16* rb = Abuf[ph & 1];
        bf16x8 af0[4], af1[4];
        #pragma unroll
        for (int rt = 0; rt < 4; rt++) {
            af0[rt] = *(const bf16x8*)&rb[(rt * 64 + lane) * 8];
            af1[rt] = *(const bf16x8*)&rb[2048 + (rt * 64 + lane) * 8];
        }
        #pragma unroll
        for (int rt = 0; rt < 4; rt++)
            #pragma unroll
            for (int ct = 0; ct < 4; ct++) {
                acc[rt][ct] = __builtin_amdgcn_mfma_f32_16x16x32_bf16(
                    af0[rt], b0[ct], acc[rt][ct], 0, 0, 0);
                acc[rt][ct] = __builtin_amdgcn_mfma_f32_16x16x32_bf16(
                    af1[rt], b1[ct], acc[rt][ct], 0, 0, 0);
            }
        barrier_lds_only();
    }

    // ---- folded chunk 8
    {
        bf16x8 bf[4];
        #pragma unroll
        for (int ct = 0; ct < 4; ct++) bf[ct] = bbase[(8 * 16 + ct) * 64];
        bf16x8 af[4];
        #pragma unroll
        for (int rt = 0; rt < 4; rt++)
            af[rt] = *(const bf16x8*)&Afold[(rt * 64 + lane) * 8];
        #pragma unroll
        for (int rt = 0; rt < 4; rt++)
            #pragma unroll
            for (int ct = 0; ct < 4; ct++)
                acc[rt][ct] = __builtin_amdgcn_mfma_f32_16x16x32_bf16(
                    af[rt], bf[ct], acc[rt][ct], 0, 0, 0);
    }

    // ---- epilogue: tanh_pade(acc) . Wout, DPP reduce, cross-wave combine
    #pragma unroll
    for (int rt = 0; rt < 4; rt++) {
        #pragma unroll
        for (int reg = 0; reg < 4; reg++) {
            float rs = 0.0f;
            #pragma unroll
            for (int ct = 0; ct < 4; ct++)
                rs += tanh_pade(acc[rt][ct][reg]) * wo[ct];
            rs = row16_reduce(rs);
            if (col16 == 0) red[w][rt * 16 + quad * 4 + reg] = rs;
        }
    }
    barrier_lds_only();

    if (tid < 64) {
        float total = red[0][tid] + red[1][tid] + red[2][tid] + red[3][tid];
        const int p = p0 + (tid >> 3), a = a0r + (tid & 7);
        out[((size_t)(b * LSEQ + p) * NCASE + n) * LSEQ + a] = total;
    }
}

// ---------------------------------------------------------------------------
extern "C" void kernel_launch(void* const* d_in, const int* in_sizes, int n_in,
                              void* d_out, int out_size, void* d_ws, size_t ws_size,
                              hipStream_t stream) {
    const float* seq  = (const float*)d_in[0];
    const float* bsc  = (const float*)d_in[1];
    const float* Wp   = (const float*)d_in[2];
    const float* bp   = (const float*)d_in[3];
    const float* Wa   = (const float*)d_in[4];
    const float* ba   = (const float*)d_in[5];
    const float* Wmid = (const float*)d_in[6];
    const float* bmid = (const float*)d_in[7];
    const float* Wout = (const float*)d_in[8];
    float* out = (float*)d_out;

    char* ws = (char*)d_ws;
    float*  lin   = (float*)(ws);                      // 1,966,080 B
    bf16x8* Bpack = (bf16x8*)(ws + 1966080);           //   589,824 B

    prep<<<624, 256, 0, stream>>>(seq, Wp, Wa, bp, ba, Wmid, bmid, lin, Bpack);
    refine_main<<<dim3(576, NCASE, BATCH), 256, 0, stream>>>(
        lin, bsc, Wout, Bpack, out);
}

// Round 10
// 153.496 us; speedup vs baseline: 1.1814x; 1.1814x over previous
//
#include <hip/hip_runtime.h>

// Problem constants (RefinementLayer1): B=2, L=192, D=768, NC=4, H=256
#define LSEQ 192
#define DIM  768
#define NCASE 4
#define HID  256
#define BATCH 2

// tanh(x) = 1 - 2/(exp2(K*x)+1), K = 2*log2(e). K is folded into Bpack so the
// refine epilogue's tanh input (acc = K*mid) needs no extra scale.
#define TANH_K 2.885390081777927f

typedef float  floatx4 __attribute__((ext_vector_type(4)));
typedef __bf16 bf16x8  __attribute__((ext_vector_type(8)));

__device__ __forceinline__ float tanh_pre(float x) {   // x already * TANH_K
    float e = __builtin_amdgcn_exp2f(x);
    return 1.0f - 2.0f * __builtin_amdgcn_rcpf(e + 1.0f);
}

// tanh addition formula: given tu=tanh(u), tv=tanh(v),
// tanh(u+v) = (tu+tv) / (1 + tu*tv).  1 trans (rcp) + 3 full-rate ops vs
// 2 trans + 2 full for the exp2 form — A-gen trans cost halves (R7/R9
// counters: VALU floor == tanh issue time; trans was 73% of it).
__device__ __forceinline__ float tanh_add(float tu, float tv) {
    float den = __builtin_fmaf(tu, tv, 1.0f);
    return (tu + tv) * __builtin_amdgcn_rcpf(den);
}

// Workgroup barrier draining ONLY lgkmcnt (LDS); global prefetches stay in
// flight. 0xC07F = vmcnt(63) expcnt(7) lgkmcnt(0).
__device__ __forceinline__ void barrier_lds_only() {
    __builtin_amdgcn_sched_barrier(0);
    __builtin_amdgcn_s_waitcnt(0xC07F);
    __builtin_amdgcn_s_barrier();
    __builtin_amdgcn_sched_barrier(0);
}

template <int CTRL>
__device__ __forceinline__ float dpp_add(float v) {
    int x = __builtin_amdgcn_update_dpp(0, __builtin_bit_cast(int, v),
                                        CTRL, 0xF, 0xF, true);
    return v + __builtin_bit_cast(float, x);
}
__device__ __forceinline__ float row16_reduce(float v) {
    v = dpp_add<0xB1>(v);    // quad_perm xor1
    v = dpp_add<0x4E>(v);    // quad_perm xor2
    v = dpp_add<0x141>(v);   // row_half_mirror
    v = dpp_add<0x140>(v);   // row_mirror
    return v;
}

// ---------------------------------------------------------------------------
// MFMA fragment layouts (m89/m91-verified, 16x16x32 bf16):
//   A: lane holds A[m = lane&15][k = (lane>>4)*8 + j]   (bf16x8)
//   B: lane holds B[k = (lane>>4)*8 + j][h = lane&15]   (bf16x8)
//   C/D: lane reg holds D[row = (lane>>4)*4 + reg][col = lane&15]
// ---------------------------------------------------------------------------

// ---------------------------------------------------------------------------
// Kernel 1 "prep": two jobs by blockIdx:
//  blocks [0,480):  lin GEMM, 4 independent waves/block; wave = one (rt,cg)
//    unit: 16 rows x 16 cols. lin = TANH(seq @ [Wp|Wa] + bias)  <-- note:
//    PRE-ACTIVATED. refine then combines via the tanh addition formula.
//    seq/W converted to bf16 hi/lo in-register, MFMA hh+lh+hl. Barrier-free.
//  blocks [480,624): pack Wmid/bmid -> Bpack bf16 B-frags, scaled by TANH_K
//    (k rows 256..259 = bs rows, k=260 = bmid row, k>260 zero).
// ---------------------------------------------------------------------------
__global__ __launch_bounds__(256) void prep(
    const float* __restrict__ seq, const float* __restrict__ Wp,
    const float* __restrict__ Wa,  const float* __restrict__ bp,
    const float* __restrict__ ba,  const float* __restrict__ Wmid,
    const float* __restrict__ bmid,
    float* __restrict__ lin, bf16x8* __restrict__ Bpack)
{
    const int blk = blockIdx.x;
    const int tid = threadIdx.x;

    if (blk >= 480) {                      // ---- pack job
        int u = (blk - 480) * 256 + tid;   // 0..36863 (one bf16x8 each)
        int lane = u & 63, f = u >> 6;
        int ct = f & 15, nk = f >> 4;      // nk = n*9 + kc
        int kc = nk % 9, n = nk / 9;
        int h = ct * 16 + (lane & 15);
        int kbase = kc * 32 + ((lane >> 4) & 3) * 8;
        bf16x8 v;
        #pragma unroll
        for (int j = 0; j < 8; j++) {
            int k = kbase + j;
            float x;
            if (k < 260)       x = Wmid[(size_t)(n * 260 + k) * 256 + h];
            else if (k == 260) x = bmid[n * 256 + h];
            else               x = 0.0f;
            v[j] = (__bf16)(TANH_K * x);
        }
        Bpack[u] = v;
        return;
    }

    // ---- lin GEMM job: unit u = blk*4 + wave, rt = u/80, cg = u%80
    const int w = tid >> 6, lane = tid & 63;
    const int u = blk * 4 + w;
    const int rt = u / 80, cg = u % 80;
    const int quad  = lane >> 4;
    const int col16 = lane & 15;

    const int arow = rt * 16 + col16;          // A: m = lane&15
    const int col  = cg * 16 + col16;          // output col 0..1279
    const float* aptr = seq + (size_t)arow * DIM + quad * 8;
    const float* wbase = (cg < 16) ? (Wp + col) : (Wa + (col - 256));
    const int    wstr  = (cg < 16) ? HID : (NCASE * HID);

    floatx4 acc = {};
    floatx4 a0 = *(const floatx4*)(aptr);
    floatx4 a1 = *(const floatx4*)(aptr + 4);
    float bv[8];
    #pragma unroll
    for (int j = 0; j < 8; j++) bv[j] = wbase[(size_t)(quad * 8 + j) * wstr];

    #pragma unroll
    for (int kc = 0; kc < 24; kc++) {
        bf16x8 ah, al, bh, bl;
        #pragma unroll
        for (int j = 0; j < 4; j++) {
            __bf16 h0 = (__bf16)a0[j];
            ah[j] = h0; al[j] = (__bf16)(a0[j] - (float)h0);
            __bf16 h1 = (__bf16)a1[j];
            ah[4 + j] = h1; al[4 + j] = (__bf16)(a1[j] - (float)h1);
        }
        #pragma unroll
        for (int j = 0; j < 8; j++) {
            __bf16 h = (__bf16)bv[j];
            bh[j] = h; bl[j] = (__bf16)(bv[j] - (float)h);
        }
        if (kc < 23) {
            a0 = *(const floatx4*)(aptr + (kc + 1) * 32);
            a1 = *(const floatx4*)(aptr + (kc + 1) * 32 + 4);
            #pragma unroll
            for (int j = 0; j < 8; j++)
                bv[j] = wbase[(size_t)((kc + 1) * 32 + quad * 8 + j) * wstr];
        }
        acc = __builtin_amdgcn_mfma_f32_16x16x32_bf16(ah, bh, acc, 0, 0, 0);
        acc = __builtin_amdgcn_mfma_f32_16x16x32_bf16(al, bh, acc, 0, 0, 0);
        acc = __builtin_amdgcn_mfma_f32_16x16x32_bf16(ah, bl, acc, 0, 0, 0);
    }
    const float bias = (cg < 16) ? bp[col] : ba[col - 256];
    #pragma unroll
    for (int reg = 0; reg < 4; reg++)
        lin[(size_t)(rt * 16 + quad * 4 + reg) * 1280 + col] =
            tanh_pre(TANH_K * (acc[reg] + bias));     // pre-activated
}

// ---------------------------------------------------------------------------
// Kernel 2: fused main (R7 structure; A-gen now via tanh addition formula).
// Block = 4 waves, 64 rows (8p x 8a) x 256 cols, fixed (b,n). A SHARED via
// LDS (each thread generates one frag slot/chunk; its OWN slot is kept in a
// register so frag rt==w skips the LDS read); cols SPLIT across waves (wave
// w owns ct w*4..w*4+3, B-frags global->regs, non-redundant). Pipelined:
// B(kc+1)/lin(kc+2) loads stay in flight across the lgkm-only barrier.
// K: 8 tanh-add chunks + 1 folded bs/bmid chunk. Epilogue: tanh(acc).Wout
// (acc = K*mid via Bpack fold), DPP reduce, cross-wave LDS combine, store.
// ---------------------------------------------------------------------------
__global__ __launch_bounds__(256, 2) void refine_main(
    const float* __restrict__ lin,        // [384][1280], PRE-TANH'd
    const float* __restrict__ base_score, // [B][L][NC][L]
    const float* __restrict__ Wout,       // [NC][256]
    const bf16x8* __restrict__ Bpack,     // packed Wmid frags (K-scaled)
    float* __restrict__ out)              // [B][L][NC][L]
{
    const int bx = blockIdx.x;            // 576 = 24*24
    const int n  = blockIdx.y;
    const int b  = blockIdx.z;
    const int ptile = bx / 24, atile = bx % 24;
    const int p0 = ptile * 8, a0r = atile * 8;

    const int tid   = threadIdx.x;
    const int w     = tid >> 6;
    const int lane  = tid & 63;
    const int quad  = lane >> 4;
    const int col16 = lane & 15;

    __shared__ __align__(16) __bf16 A0[256 * 8];   // 4 KB frag buf (even kc)
    __shared__ __align__(16) __bf16 A1[256 * 8];   // 4 KB frag buf (odd kc)
    __shared__ float red[4][64];

    // A-gen: thread owns frag slot tid: row = w*16 + col16, k-slice quad*8..+7
    const int row_gen = w * 16 + col16;
    const int pg = p0 + (row_gen >> 3), ag = a0r + (row_gen & 7);
    const float* hp_ptr = lin + (size_t)(b * LSEQ + pg) * 1280 + quad * 8;
    const float* ha_ptr = lin + (size_t)(b * LSEQ + ag) * 1280 + 256 + n * 256 + quad * 8;

    // B frags for wave w: index ((n*9 + kc)*16 + w*4 + ct)*64 + lane
    const bf16x8* bbase = Bpack + ((size_t)(n * 9) * 16 + w * 4) * 64 + lane;

    // ---- prologue
    float bs4[4], wo[4];
    #pragma unroll
    for (int j = 0; j < 4; j++)
        bs4[j] = base_score[((size_t)(b * LSEQ + pg) * NCASE + j) * LSEQ + ag];
    #pragma unroll
    for (int ct = 0; ct < 4; ct++)
        wo[ct] = Wout[n * 256 + w * 64 + ct * 16 + col16];

    bf16x8 bcur[4];
    #pragma unroll
    for (int ct = 0; ct < 4; ct++) bcur[ct] = bbase[ct * 64];

    floatx4 hp0 = *(const floatx4*)(hp_ptr);
    floatx4 hp1 = *(const floatx4*)(hp_ptr + 4);
    floatx4 ha0 = *(const floatx4*)(ha_ptr);
    floatx4 ha1 = *(const floatx4*)(ha_ptr + 4);
    bf16x8 av_cur;                        // this thread's own frag (rt == w)
    {   // av(0) -> A0
        #pragma unroll
        for (int j = 0; j < 4; j++) {
            av_cur[j]     = (__bf16)tanh_add(hp0[j], ha0[j]);
            av_cur[4 + j] = (__bf16)tanh_add(hp1[j], ha1[j]);
        }
        *(bf16x8*)&A0[tid * 8] = av_cur;
    }
    // inputs for chunk 1
    hp0 = *(const floatx4*)(hp_ptr + 32);
    hp1 = *(const floatx4*)(hp_ptr + 36);
    ha0 = *(const floatx4*)(ha_ptr + 32);
    ha1 = *(const floatx4*)(ha_ptr + 36);
    barrier_lds_only();

    floatx4 acc[4][4] = {};   // [rt][ct]

    #pragma unroll
    for (int kc = 0; kc < 9; kc++) {
        // B prefetch for chunk kc+1 (stays in flight across the barrier)
        bf16x8 bnext[4];
        if (kc < 8) {
            #pragma unroll
            for (int ct = 0; ct < 4; ct++)
                bnext[ct] = bbase[((kc + 1) * 16 + ct) * 64];
        }
        // generate av(kc+1) into the other buffer (overlaps MFMA below)
        bf16x8 av_next;
        if (kc < 7) {
            if (kc < 6) {                 // prefetch inputs for chunk kc+2
                floatx4 u0 = hp0, u1 = hp1, v0 = ha0, v1 = ha1;
                hp0 = *(const floatx4*)(hp_ptr + (kc + 2) * 32);
                hp1 = *(const floatx4*)(hp_ptr + (kc + 2) * 32 + 4);
                ha0 = *(const floatx4*)(ha_ptr + (kc + 2) * 32);
                ha1 = *(const floatx4*)(ha_ptr + (kc + 2) * 32 + 4);
                #pragma unroll
                for (int j = 0; j < 4; j++) {
                    av_next[j]     = (__bf16)tanh_add(u0[j], v0[j]);
                    av_next[4 + j] = (__bf16)tanh_add(u1[j], v1[j]);
                }
            } else {
                #pragma unroll
                for (int j = 0; j < 4; j++) {
                    av_next[j]     = (__bf16)tanh_add(hp0[j], ha0[j]);
                    av_next[4 + j] = (__bf16)tanh_add(hp1[j], ha1[j]);
                }
            }
            __bf16* buf = ((kc + 1) & 1) ? A1 : A0;
            *(bf16x8*)&buf[tid * 8] = av_next;
        } else if (kc == 7) {             // folded chunk: A = [bs(4), 1, 0...]
            av_next = bf16x8{};
            if (quad == 0) {
                #pragma unroll
                for (int j = 0; j < 4; j++) av_next[j] = (__bf16)bs4[j];
                av_next[4] = (__bf16)1.0f;
            }
            *(bf16x8*)&A0[tid * 8] = av_next;   // (7+1)&1 == 0
        }

        // MFMA(kc) from buf[kc&1]; frag rt==w from register (own slot)
        const __bf16* rb = (kc & 1) ? A1 : A0;
        bf16x8 af[4];
        #pragma unroll
        for (int rt = 0; rt < 4; rt++) {
            if (rt == w) af[rt] = av_cur;
            else         af[rt] = *(const bf16x8*)&rb[(rt * 64 + lane) * 8];
        }
        #pragma unroll
        for (int rt = 0; rt < 4; rt++)
            #pragma unroll
            for (int ct = 0; ct < 4; ct++)
                acc[rt][ct] = __builtin_amdgcn_mfma_f32_16x16x32_bf16(
                    af[rt], bcur[ct], acc[rt][ct], 0, 0, 0);
        #pragma unroll
        for (int ct = 0; ct < 4; ct++) bcur[ct] = bnext[ct];
        if (kc < 8) { av_cur = av_next; barrier_lds_only(); }
    }

    // ---- epilogue: tanh(acc) . Wout (acc = K*mid), DPP reduce, combine
    #pragma unroll
    for (int rt = 0; rt < 4; rt++) {
        #pragma unroll
        for (int reg = 0; reg < 4; reg++) {
            float rs = 0.0f;
            #pragma unroll
            for (int ct = 0; ct < 4; ct++)
                rs += tanh_pre(acc[rt][ct][reg]) * wo[ct];
            rs = row16_reduce(rs);
            if (col16 == 0) red[w][rt * 16 + quad * 4 + reg] = rs;
        }
    }
    barrier_lds_only();

    if (tid < 64) {
        float total = red[0][tid] + red[1][tid] + red[2][tid] + red[3][tid];
        const int p = p0 + (tid >> 3), a = a0r + (tid & 7);
        out[((size_t)(b * LSEQ + p) * NCASE + n) * LSEQ + a] = total;
    }
}

// ---------------------------------------------------------------------------
extern "C" void kernel_launch(void* const* d_in, const int* in_sizes, int n_in,
                              void* d_out, int out_size, void* d_ws, size_t ws_size,
                              hipStream_t stream) {
    const float* seq  = (const float*)d_in[0];
    const float* bsc  = (const float*)d_in[1];
    const float* Wp   = (const float*)d_in[2];
    const float* bp   = (const float*)d_in[3];
    const float* Wa   = (const float*)d_in[4];
    const float* ba   = (const float*)d_in[5];
    const float* Wmid = (const float*)d_in[6];
    const float* bmid = (const float*)d_in[7];
    const float* Wout = (const float*)d_in[8];
    float* out = (float*)d_out;

    char* ws = (char*)d_ws;
    float*  lin   = (float*)(ws);                      // 1,966,080 B
    bf16x8* Bpack = (bf16x8*)(ws + 1966080);           //   589,824 B

    prep<<<624, 256, 0, stream>>>(seq, Wp, Wa, bp, ba, Wmid, bmid, lin, Bpack);
    refine_main<<<dim3(576, NCASE, BATCH), 256, 0, stream>>>(
        lin, bsc, Wout, Bpack, out);
}

// Round 11
// 150.527 us; speedup vs baseline: 1.2047x; 1.0197x over previous
//
#include <hip/hip_runtime.h>

// Problem constants (RefinementLayer1): B=2, L=192, D=768, NC=4, H=256
#define LSEQ 192
#define DIM  768
#define NCASE 4
#define HID  256
#define BATCH 2

// tanh(x) = 1 - 2/(exp2(K*x)+1), K = 2*log2(e). K folded into Bpack so the
// refine epilogue's tanh input (acc = K*mid) needs no extra scale.
#define TANH_K 2.885390081777927f

typedef float  floatx4 __attribute__((ext_vector_type(4)));
typedef __bf16 bf16x8  __attribute__((ext_vector_type(8)));
typedef __bf16 bf16x4  __attribute__((ext_vector_type(4)));

__device__ __forceinline__ float tanh_pre(float x) {   // x already * TANH_K
    float e = __builtin_amdgcn_exp2f(x);
    return 1.0f - 2.0f * __builtin_amdgcn_rcpf(e + 1.0f);
}

// tanh(u+v) = (tu+tv)/(1+tu*tv) from tu=tanh(u), tv=tanh(v): 1 trans + 3 ops.
__device__ __forceinline__ float tanh_add(float tu, float tv) {
    float den = __builtin_fmaf(tu, tv, 1.0f);
    return (tu + tv) * __builtin_amdgcn_rcpf(den);
}

// Workgroup barrier draining ONLY lgkmcnt (LDS); global prefetches stay in
// flight. 0xC07F = vmcnt(63) expcnt(7) lgkmcnt(0).
__device__ __forceinline__ void barrier_lds_only() {
    __builtin_amdgcn_sched_barrier(0);
    __builtin_amdgcn_s_waitcnt(0xC07F);
    __builtin_amdgcn_s_barrier();
    __builtin_amdgcn_sched_barrier(0);
}

template <int CTRL>
__device__ __forceinline__ float dpp_add(float v) {
    int x = __builtin_amdgcn_update_dpp(0, __builtin_bit_cast(int, v),
                                        CTRL, 0xF, 0xF, true);
    return v + __builtin_bit_cast(float, x);
}
__device__ __forceinline__ float row16_reduce(float v) {
    v = dpp_add<0xB1>(v);    // quad_perm xor1
    v = dpp_add<0x4E>(v);    // quad_perm xor2
    v = dpp_add<0x141>(v);   // row_half_mirror
    v = dpp_add<0x140>(v);   // row_mirror
    return v;
}

// ---------------------------------------------------------------------------
// MFMA fragment layouts (m89/m91-verified, 16x16x32 bf16):
//   A: lane holds A[m = lane&15][k = (lane>>4)*8 + j]   (bf16x8)
//   B: lane holds B[k = (lane>>4)*8 + j][h = lane&15]   (bf16x8)
//   C/D: lane reg holds D[row = (lane>>4)*4 + reg][col = lane&15]
// ---------------------------------------------------------------------------

// ---------------------------------------------------------------------------
// Kernel 1 "prep": two jobs by blockIdx:
//  blocks [0,480):  lin GEMM, 4 independent waves/block; wave = one (rt,cg)
//    unit: 16 rows x 16 cols. lin = TANH(seq @ [Wp|Wa] + bias) (pre-activated
//    for refine's tanh addition formula). bf16 hi/lo in-register, hh+lh+hl.
//  blocks [480,624): pack Wmid/bmid -> Bpack bf16 B-frags, scaled by TANH_K
//    (k rows 256..259 = bs rows, k=260 = bmid row, k>260 zero).
// ---------------------------------------------------------------------------
__global__ __launch_bounds__(256) void prep(
    const float* __restrict__ seq, const float* __restrict__ Wp,
    const float* __restrict__ Wa,  const float* __restrict__ bp,
    const float* __restrict__ ba,  const float* __restrict__ Wmid,
    const float* __restrict__ bmid,
    float* __restrict__ lin, bf16x8* __restrict__ Bpack)
{
    const int blk = blockIdx.x;
    const int tid = threadIdx.x;

    if (blk >= 480) {                      // ---- pack job
        int u = (blk - 480) * 256 + tid;   // 0..36863 (one bf16x8 each)
        int lane = u & 63, f = u >> 6;
        int ct = f & 15, nk = f >> 4;      // nk = n*9 + kc
        int kc = nk % 9, n = nk / 9;
        int h = ct * 16 + (lane & 15);
        int kbase = kc * 32 + ((lane >> 4) & 3) * 8;
        bf16x8 v;
        #pragma unroll
        for (int j = 0; j < 8; j++) {
            int k = kbase + j;
            float x;
            if (k < 260)       x = Wmid[(size_t)(n * 260 + k) * 256 + h];
            else if (k == 260) x = bmid[n * 256 + h];
            else               x = 0.0f;
            v[j] = (__bf16)(TANH_K * x);
        }
        Bpack[u] = v;
        return;
    }

    // ---- lin GEMM job: unit u = blk*4 + wave, rt = u/80, cg = u%80
    const int w = tid >> 6, lane = tid & 63;
    const int u = blk * 4 + w;
    const int rt = u / 80, cg = u % 80;
    const int quad  = lane >> 4;
    const int col16 = lane & 15;

    const int arow = rt * 16 + col16;          // A: m = lane&15
    const int col  = cg * 16 + col16;          // output col 0..1279
    const float* aptr = seq + (size_t)arow * DIM + quad * 8;
    const float* wbase = (cg < 16) ? (Wp + col) : (Wa + (col - 256));
    const int    wstr  = (cg < 16) ? HID : (NCASE * HID);

    floatx4 acc = {};
    floatx4 a0 = *(const floatx4*)(aptr);
    floatx4 a1 = *(const floatx4*)(aptr + 4);
    float bv[8];
    #pragma unroll
    for (int j = 0; j < 8; j++) bv[j] = wbase[(size_t)(quad * 8 + j) * wstr];

    #pragma unroll
    for (int kc = 0; kc < 24; kc++) {
        bf16x8 ah, al, bh, bl;
        #pragma unroll
        for (int j = 0; j < 4; j++) {
            __bf16 h0 = (__bf16)a0[j];
            ah[j] = h0; al[j] = (__bf16)(a0[j] - (float)h0);
            __bf16 h1 = (__bf16)a1[j];
            ah[4 + j] = h1; al[4 + j] = (__bf16)(a1[j] - (float)h1);
        }
        #pragma unroll
        for (int j = 0; j < 8; j++) {
            __bf16 h = (__bf16)bv[j];
            bh[j] = h; bl[j] = (__bf16)(bv[j] - (float)h);
        }
        if (kc < 23) {
            a0 = *(const floatx4*)(aptr + (kc + 1) * 32);
            a1 = *(const floatx4*)(aptr + (kc + 1) * 32 + 4);
            #pragma unroll
            for (int j = 0; j < 8; j++)
                bv[j] = wbase[(size_t)((kc + 1) * 32 + quad * 8 + j) * wstr];
        }
        acc = __builtin_amdgcn_mfma_f32_16x16x32_bf16(ah, bh, acc, 0, 0, 0);
        acc = __builtin_amdgcn_mfma_f32_16x16x32_bf16(al, bh, acc, 0, 0, 0);
        acc = __builtin_amdgcn_mfma_f32_16x16x32_bf16(ah, bl, acc, 0, 0, 0);
    }
    const float bias = (cg < 16) ? bp[col] : ba[col - 256];
    #pragma unroll
    for (int reg = 0; reg < 4; reg++)
        lin[(size_t)(rt * 16 + quad * 4 + reg) * 1280 + col] =
            tanh_pre(TANH_K * (acc[reg] + bias));     // pre-activated
}

// ---------------------------------------------------------------------------
// Kernel 2: fused main — 512 threads / 8 waves per block (R10 was 4 waves;
// all three 4-wave dataflows pinned at 77-84 us with pipes running back-to-
// back at ~9 waves/CU). Wave owns 2 ct-frags (acc 32 AGPRs, total regs ~100
// -> 2 blocks/CU = 16 waves/CU = 4/SIMD, double R10's residency; per-wave
// barrier-to-barrier segment halves). Tile = 64 rows (8p x 8a) x 256 cols,
// fixed (b,n). A SHARED via LDS: each thread tanh_add-generates a HALF slot
// (4 elems). B-frags global->regs, non-redundant (8 waves x 2 = 16/chunk).
// lgkm-only barriers; B(kc+1)/lin(kc+1) prefetches stay in flight.
// K: 8 tanh chunks + folded bs/bmid chunk. Epilogue: tanh(acc).Wout,
// DPP reduce, 8-way cross-wave LDS combine, store.
// ---------------------------------------------------------------------------
__global__ __launch_bounds__(512, 4) void refine_main(
    const float* __restrict__ lin,        // [384][1280], PRE-TANH'd
    const float* __restrict__ base_score, // [B][L][NC][L]
    const float* __restrict__ Wout,       // [NC][256]
    const bf16x8* __restrict__ Bpack,     // packed Wmid frags (K-scaled)
    float* __restrict__ out)              // [B][L][NC][L]
{
    const int bx = blockIdx.x;            // 576 = 24*24
    const int n  = blockIdx.y;
    const int b  = blockIdx.z;
    const int ptile = bx / 24, atile = bx % 24;
    const int p0 = ptile * 8, a0r = atile * 8;

    const int tid   = threadIdx.x;
    const int w     = tid >> 6;           // wave 0..7, owns ct = w*2, w*2+1
    const int lane  = tid & 63;
    const int quad  = lane >> 4;
    const int col16 = lane & 15;

    __shared__ __align__(16) __bf16 A0[256 * 8];   // 4 KB frag buf (even kc)
    __shared__ __align__(16) __bf16 A1[256 * 8];   // 4 KB frag buf (odd kc)
    __shared__ float red[8][64];

    // A-gen half-slot: slot s = tid>>1 (l = s&63), half = tid&1.
    // Slot row = (s>>6)*16 + (l&15); this thread's k-slice = (l>>4)*8 + half*4.
    const int s_g    = tid >> 1;
    const int h2     = tid & 1;
    const int l_g    = s_g & 63;
    const int m_gen  = ((s_g >> 6) << 4) + (l_g & 15);
    const int kq     = (l_g >> 4) * 8 + h2 * 4;
    const int quad_g = l_g >> 4;

    const int pg = p0 + (m_gen >> 3), ag = a0r + (m_gen & 7);
    const float* hp_ptr = lin + (size_t)(b * LSEQ + pg) * 1280 + kq;
    const float* ha_ptr = lin + (size_t)(b * LSEQ + ag) * 1280 + 256 + n * 256 + kq;

    // B frags for wave w: index ((n*9 + kc)*16 + w*2 + ct)*64 + lane
    const bf16x8* bbase = Bpack + ((size_t)(n * 9) * 16 + w * 2) * 64 + lane;

    // ---- prologue
    float bs4[4] = {};
    if (quad_g == 0 && h2 == 0) {
        #pragma unroll
        for (int j = 0; j < 4; j++)
            bs4[j] = base_score[((size_t)(b * LSEQ + pg) * NCASE + j) * LSEQ + ag];
    }
    float wo[2];
    #pragma unroll
    for (int ct = 0; ct < 2; ct++)
        wo[ct] = Wout[n * 256 + w * 32 + ct * 16 + col16];

    bf16x8 bcur[2];
    #pragma unroll
    for (int ct = 0; ct < 2; ct++) bcur[ct] = bbase[ct * 64];

    floatx4 hp = *(const floatx4*)(hp_ptr);
    floatx4 ha = *(const floatx4*)(ha_ptr);
    {   // av(0) -> A0 (half-slot = 8 bytes at tid*4 bf16 elems)
        bf16x4 av;
        #pragma unroll
        for (int j = 0; j < 4; j++) av[j] = (__bf16)tanh_add(hp[j], ha[j]);
        *(bf16x4*)&A0[tid * 4] = av;
    }
    hp = *(const floatx4*)(hp_ptr + 32);   // chunk 1 inputs
    ha = *(const floatx4*)(ha_ptr + 32);
    barrier_lds_only();

    floatx4 acc[4][2] = {};   // [rt][ct]

    #pragma unroll
    for (int kc = 0; kc < 9; kc++) {
        // B prefetch for chunk kc+1 (stays in flight across the barrier)
        bf16x8 bnext[2];
        if (kc < 8) {
            #pragma unroll
            for (int ct = 0; ct < 2; ct++)
                bnext[ct] = bbase[((kc + 1) * 16 + ct) * 64];
        }
        // generate av(kc+1) into the other buffer (overlaps MFMA below)
        if (kc < 7) {
            floatx4 u0 = hp, v0 = ha;
            if (kc < 6) {                 // prefetch inputs for chunk kc+2
                hp = *(const floatx4*)(hp_ptr + (kc + 2) * 32);
                ha = *(const floatx4*)(ha_ptr + (kc + 2) * 32);
            }
            bf16x4 av;
            #pragma unroll
            for (int j = 0; j < 4; j++) av[j] = (__bf16)tanh_add(u0[j], v0[j]);
            __bf16* buf = ((kc + 1) & 1) ? A1 : A0;
            *(bf16x4*)&buf[tid * 4] = av;
        } else if (kc == 7) {             // folded chunk: A = [bs(4), 1, 0...]
            bf16x4 av = {};
            if (quad_g == 0) {
                if (h2 == 0) {
                    #pragma unroll
                    for (int j = 0; j < 4; j++) av[j] = (__bf16)bs4[j];
                } else {
                    av[0] = (__bf16)1.0f;  // k = 4 pairs with bmid row
                }
            }
            *(bf16x4*)&A0[tid * 4] = av;   // (7+1)&1 == 0
        }

        // MFMA(kc) from buf[kc&1]
        const __bf16* rb = (kc & 1) ? A1 : A0;
        bf16x8 af[4];
        #pragma unroll
        for (int rt = 0; rt < 4; rt++)
            af[rt] = *(const bf16x8*)&rb[(rt * 64 + lane) * 8];
        #pragma unroll
        for (int rt = 0; rt < 4; rt++)
            #pragma unroll
            for (int ct = 0; ct < 2; ct++)
                acc[rt][ct] = __builtin_amdgcn_mfma_f32_16x16x32_bf16(
                    af[rt], bcur[ct], acc[rt][ct], 0, 0, 0);
        #pragma unroll
        for (int ct = 0; ct < 2; ct++) bcur[ct] = bnext[ct];
        if (kc < 8) barrier_lds_only();
    }

    // ---- epilogue: tanh(acc) . Wout (acc = K*mid), DPP reduce, combine
    #pragma unroll
    for (int rt = 0; rt < 4; rt++) {
        #pragma unroll
        for (int reg = 0; reg < 4; reg++) {
            float rs = tanh_pre(acc[rt][0][reg]) * wo[0]
                     + tanh_pre(acc[rt][1][reg]) * wo[1];
            rs = row16_reduce(rs);
            if (col16 == 0) red[w][rt * 16 + quad * 4 + reg] = rs;
        }
    }
    barrier_lds_only();

    if (tid < 64) {
        float total = red[0][tid] + red[1][tid] + red[2][tid] + red[3][tid]
                    + red[4][tid] + red[5][tid] + red[6][tid] + red[7][tid];
        const int p = p0 + (tid >> 3), a = a0r + (tid & 7);
        out[((size_t)(b * LSEQ + p) * NCASE + n) * LSEQ + a] = total;
    }
}

// ---------------------------------------------------------------------------
extern "C" void kernel_launch(void* const* d_in, const int* in_sizes, int n_in,
                              void* d_out, int out_size, void* d_ws, size_t ws_size,
                              hipStream_t stream) {
    const float* seq  = (const float*)d_in[0];
    const float* bsc  = (const float*)d_in[1];
    const float* Wp   = (const float*)d_in[2];
    const float* bp   = (const float*)d_in[3];
    const float* Wa   = (const float*)d_in[4];
    const float* ba   = (const float*)d_in[5];
    const float* Wmid = (const float*)d_in[6];
    const float* bmid = (const float*)d_in[7];
    const float* Wout = (const float*)d_in[8];
    float* out = (float*)d_out;

    char* ws = (char*)d_ws;
    float*  lin   = (float*)(ws);                      // 1,966,080 B
    bf16x8* Bpack = (bf16x8*)(ws + 1966080);           //   589,824 B

    prep<<<624, 256, 0, stream>>>(seq, Wp, Wa, bp, ba, Wmid, bmid, lin, Bpack);
    refine_main<<<dim3(576, NCASE, BATCH), 512, 0, stream>>>(
        lin, bsc, Wout, Bpack, out);
}